// Round 15
// baseline (113.075 us; speedup 1.0000x reference)
//
#include <hip/hip_runtime.h>

#define HIDDEN 512
#define HEADS 8
#define DK 64
#define S_ 1024
#define NEGV -1000000000.0f

typedef _Float16 half8 __attribute__((ext_vector_type(8)));
typedef _Float16 half4 __attribute__((ext_vector_type(4)));
typedef _Float16 half2_t __attribute__((ext_vector_type(2)));
typedef float f32x4 __attribute__((ext_vector_type(4)));
typedef float f32x2 __attribute__((ext_vector_type(2)));
typedef int i32x4 __attribute__((ext_vector_type(4)));

// async global->LDS, 16B/lane: LDS dest = uniform base + lane*16 (linear);
// global src is per-lane (used for gather + bank-deswizzle).
__device__ __forceinline__ void gload16(const void* g, void* l) {
  __builtin_amdgcn_global_load_lds(
      (const __attribute__((address_space(1))) unsigned int*)g,
      (__attribute__((address_space(3))) unsigned int*)l, 16, 0, 0);
}

// ---------------- weights fp32 -> fp16 ----------------
__global__ __launch_bounds__(256) void cvt4(const float* __restrict__ a0,
                                            const float* __restrict__ a1,
                                            const float* __restrict__ a2,
                                            const float* __restrict__ a3,
                                            _Float16* o0, _Float16* o1, _Float16* o2, _Float16* o3) {
  const float* src = blockIdx.y == 0 ? a0 : (blockIdx.y == 1 ? a1 : (blockIdx.y == 2 ? a2 : a3));
  _Float16* dst = blockIdx.y == 0 ? o0 : (blockIdx.y == 1 ? o1 : (blockIdx.y == 2 ? o2 : o3));
  int i = (blockIdx.x * 256 + threadIdx.x) * 4;
  float4 v = *(const float4*)(src + i);
  half4 h = {(_Float16)v.x, (_Float16)v.y, (_Float16)v.z, (_Float16)v.w};
  *(half4*)(dst + i) = h;
}

// ---------------- fuse gmask+subsq -> fp16 (row layout) ----------------
__global__ __launch_bounds__(256) void fusemask(const int* __restrict__ gm,
                                                const float* __restrict__ sq,
                                                _Float16* __restrict__ msk) {
  int i = (blockIdx.x * 256 + threadIdx.x) * 4;
  i32x4 g = *(const i32x4*)(gm + i);
  f32x4 s = *(const f32x4*)(sq + i);
  half4 o;
#pragma unroll
  for (int j = 0; j < 4; j++)
    o[j] = (_Float16)(g[j] == 0 ? -30000.0f : s[j]);
  *(half4*)(msk + i) = o;
}

// ---------------- repack bias fp32 -> fp16 streaming tiles [bh][gg][kt][16][64] ----------------
// Block = (bh,gg): reads 16 full 4KB rows (page-sequential), writes 32KB
// contiguous. attn wave gg then streams consecutive 2KB tiles along kt.
__global__ __launch_bounds__(256) void repack_bias(const float* __restrict__ bias,
                                                   _Float16* __restrict__ cb) {
  int blk = blockIdx.x;           // bh*64 + gg
  int bh = blk >> 6, gg = blk & 63;
  int t = threadIdx.x;
  int kt = t >> 4, k64 = (t & 15) * 4;
  const float* src = bias + ((size_t)bh * S_ + gg * 16) * S_;
  _Float16* dst = cb + (((size_t)(bh * 64 + gg)) * 16) * 1024;
#pragma unroll 4
  for (int r = 0; r < 16; r++) {
    f32x4 v = *(const f32x4*)(src + (size_t)r * S_ + t * 4);
    half4 hv = {(_Float16)v[0], (_Float16)v[1], (_Float16)v[2], (_Float16)v[3]};
    *(half4*)(dst + (size_t)kt * 1024 + r * 64 + k64) = hv;
  }
}

// ---------------- QKV projection v3: fp32 X staged via gload16, fp16 W ----------------
// Drops the cvt3 pass. X tile [16][32]f32 = 2KB/wave (2 gloads, XOR-swizzled
// source by row&7 over 8x16B units); converted to fp16 in-register after LDS.
__global__ __launch_bounds__(256) void proj_qkv3(
    const float* __restrict__ qf, const float* __restrict__ kf,
    const float* __restrict__ vf,
    const _Float16* __restrict__ wq, const _Float16* __restrict__ wk,
    const _Float16* __restrict__ wv,
    const float* __restrict__ bq, const float* __restrict__ bk,
    const float* __restrict__ bv,
    _Float16* __restrict__ qh, _Float16* __restrict__ kh, _Float16* __restrict__ vt) {
  int m0 = blockIdx.x * 64;
  int nb = blockIdx.y;
  int which = nb >> 3;
  int n0 = (nb & 7) * 64;
  const float* X = which == 0 ? qf : (which == 1 ? kf : vf);
  const _Float16* W = which == 0 ? wq : (which == 1 ? wk : wv);
  const float* bias = which == 0 ? bq : (which == 1 ? bk : bv);

  int tid = threadIdx.x;
  int wave = tid >> 6, lane = tid & 63;
  int r16 = lane & 15, quad = lane >> 4;

  // LDS: X dbuf 2x8K [0,16384) | W dbuf 2x4K [16384,24576) | T 9216 [24576,..)
  __shared__ __align__(16) char SM[33792];
  _Float16(*T)[72] = (_Float16(*)[72])(SM + 24576);

  // X staging: 2 gloads/wave; lane i of gload c covers row c*8+(i>>3),
  // phys unit i&7 <- logical unit (i&7)^(i>>3)  (8 units of 16B per 32-f row)
  int xrow = lane >> 3;            // 0..7
  int xu = (lane & 7) ^ xrow;      // pre-swizzled logical unit
  // W staging (proj_qkv2-proven): 1 gload/wave
  int rl = lane >> 2;
  int ku = lane & 3;
  int kup = ku ^ ((rl >> 1) & 3);

  const float* Xg0 = X + (size_t)(m0 + wave * 16 + xrow) * HIDDEN + xu * 4;
  const float* Xg1 = X + (size_t)(m0 + wave * 16 + 8 + xrow) * HIDDEN + xu * 4;
  const _Float16* Wg = W + (size_t)(n0 + wave * 16 + rl) * HIDDEN + kup * 8;

  auto stage = [&](int k0, int buf) __attribute__((always_inline)) {
    gload16(Xg0 + k0, SM + buf * 8192 + wave * 2048);
    gload16(Xg1 + k0, SM + buf * 8192 + wave * 2048 + 1024);
    gload16(Wg + k0, SM + 16384 + buf * 4096 + wave * 1024);
  };

  f32x4 acc[4] = {};
  stage(0, 0);
  int sw = (r16 >> 1) & 3;
  int xk = r16 & 7;  // X read swizzle key

  for (int t = 0; t < 16; t++) {
    int k0n = (t < 15) ? (t + 1) * 32 : 0;
    stage(k0n, (t + 1) & 1);
    asm volatile("s_waitcnt vmcnt(3)" ::: "memory");
    __builtin_amdgcn_sched_barrier(0);
    __builtin_amdgcn_s_barrier();

    int buf = t & 1;
    const float* XT = (const float*)(SM + buf * 8192 + wave * 2048);
    const _Float16* WT = (const _Float16*)(SM + 16384 + buf * 4096);
    f32x4 lo = *(const f32x4*)&XT[r16 * 32 + (((2 * quad) ^ xk) << 2)];
    f32x4 hi = *(const f32x4*)&XT[r16 * 32 + (((2 * quad + 1) ^ xk) << 2)];
    half8 a = {(_Float16)lo[0], (_Float16)lo[1], (_Float16)lo[2], (_Float16)lo[3],
               (_Float16)hi[0], (_Float16)hi[1], (_Float16)hi[2], (_Float16)hi[3]};
#pragma unroll
    for (int nt = 0; nt < 4; nt++) {
      half8 bfr = *(const half8*)&WT[(nt * 16 + r16) * 32 + ((quad ^ sw) << 3)];
      acc[nt] = __builtin_amdgcn_mfma_f32_16x16x32_f16(a, bfr, acc[nt], 0, 0, 0);
    }
    __builtin_amdgcn_s_barrier();
  }
  asm volatile("s_waitcnt vmcnt(0)" ::: "memory");

  if (which < 2) {
    _Float16* OUT = which == 0 ? qh : kh;
    float scale = which == 0 ? 0.125f : 1.0f;
#pragma unroll
    for (int nt = 0; nt < 4; nt++) {
      int gcol = n0 + nt * 16 + r16;
      float bv_ = bias[gcol];
      int h = gcol >> 6, d = gcol & 63;
#pragma unroll
      for (int r = 0; r < 4; r++) {
        int grow = m0 + wave * 16 + quad * 4 + r;
        int bb = grow >> 10, s = grow & 1023;
        float val = (acc[nt][r] + bv_) * scale;
        OUT[((bb * HEADS + h) * S_ + s) * DK + d] = (_Float16)val;
      }
    }
  } else {
#pragma unroll
    for (int nt = 0; nt < 4; nt++) {
      int lc = nt * 16 + r16;
      float bv_ = bias[n0 + lc];
#pragma unroll
      for (int r = 0; r < 4; r++) {
        int lr = wave * 16 + quad * 4 + r;
        T[lr][lc] = (_Float16)(acc[nt][r] + bv_);
      }
    }
    __syncthreads();
    int dl = tid >> 2;
    int s4 = (tid & 3) * 16;
    _Float16 tmp[16];
#pragma unroll
    for (int i = 0; i < 16; i++) tmp[i] = T[s4 + i][dl];
    int h = n0 >> 6;
    int bb = m0 >> 10;
    int s0 = m0 & 1023;
    _Float16* p = vt + ((bb * HEADS + h) * DK + dl) * S_ + s0 + s4;
    *(half8*)(p) = *(half8*)(tmp);
    *(half8*)(p + 8) = *(half8*)(tmp + 8);
  }
}

// ---------------- attention v14: streaming fp16 cb tiles + clump pipeline ----------------
// grid 512 x 256 thr (4 waves), 2 blocks/CU. Block = 64 q-rows x full kv;
// bh&7 == xcd. Everything double-buffered; clump = 8 gloads/wave
// (K2,V2,cb2,msk2) for tile t+1; vmcnt(8) retires all older (R10/R14-proven).
// cb = fp16 bias tiles, CONSECUTIVE 2KB along kt (repack output, L3-warm).
__global__ __launch_bounds__(256) void attn14(
    const _Float16* __restrict__ qh, const _Float16* __restrict__ kh,
    const _Float16* __restrict__ vt,
    const _Float16* __restrict__ cb, const _Float16* __restrict__ msk,
    _Float16* __restrict__ ao) {
  int id = blockIdx.x;
  int bh = (((id >> 3) & 3) << 3) | (id & 7);  // bh&7 == dispatch xcd
  int qtile = id >> 5;                         // 0..15
  int b = bh >> 3, h = bh & 7;
  int tid = threadIdx.x;
  int wave = tid >> 6, lane = tid & 63;
  int col = lane & 15, quad = lane >> 4;
  int gg = qtile * 4 + wave;                   // global 16-row group 0..63
  int q0w = qtile * 64 + wave * 16;
  int q = q0w + col;
  int xr = col & 7;
  int lr8 = lane >> 3;
  int u8 = (lane & 7) ^ lr8;

  // LDS: K dbuf 2x8K [0,16K) | V dbuf 2x8K [16K,32K) | cb dbuf 2x8K [32K,48K)
  //      msk dbuf 2x8K [48K,64K) | P2 5K [64K,69K)  => 70656 B, 2 blocks/CU
  __shared__ __align__(16) char SMEM[70656];
  unsigned(*P2)[16][20] = (unsigned(*)[16][20])(SMEM + 65536);

  const _Float16* Q = qh + ((size_t)bh * S_ + q) * DK;
  const _Float16* K = kh + (size_t)bh * S_ * DK;
  const _Float16* V = vt + (size_t)bh * DK * S_;
  const _Float16* CBw = cb + (((size_t)(bh * 64 + gg)) * 16) * 1024;  // +tt*1024
  const _Float16* MSrow = msk + ((size_t)b * S_ + q0w) * S_;

  half8 qf0 = *(const half8*)(Q + quad * 8);
  half8 qf1 = *(const half8*)(Q + 32 + quad * 8);

  f32x4 acc[4] = {};  // out^T: acc[nt][r] = out[d = nt*16+quad*4+r][q]
  float m_r = -1e38f, l_r = 0.0f;

  // one clump = exactly 8 gloads for tile tt into buffer buf
  auto stage_clump = [&](int tt, int buf) __attribute__((always_inline)) {
    int kb = tt * 64;
#pragma unroll
    for (int cc = 0; cc < 2; cc++) {
      int c = wave + cc * 4;
      int row = c * 8 + lr8;
      gload16(K + (size_t)(kb + row) * DK + u8 * 8, SMEM + buf * 8192 + c * 1024);
      gload16(V + (size_t)row * S_ + kb + u8 * 8,
              SMEM + 16384 + buf * 8192 + c * 1024);
    }
#pragma unroll
    for (int c = 0; c < 2; c++) {
      int row = c * 8 + lr8;  // q-local row 0..15
      gload16(CBw + (size_t)tt * 1024 + row * 64 + u8 * 8,
              SMEM + 32768 + buf * 8192 + wave * 2048 + c * 1024);
      gload16(MSrow + (size_t)row * S_ + kb + u8 * 8,
              SMEM + 49152 + buf * 8192 + wave * 2048 + c * 1024);
    }
  };

  stage_clump(0, 0);  // prologue

  for (int t = 0; t < 16; t++) {
    stage_clump((t + 1) & 15, (t + 1) & 1);  // t=15 wraps (dummy, keeps count)

    // retire everything older than the clump just issued (= tile t's clump)
    asm volatile("s_waitcnt vmcnt(8)" ::: "memory");
    __builtin_amdgcn_sched_barrier(0);
    __builtin_amdgcn_s_barrier();

    int buf = t & 1;
    _Float16* Klds = (_Float16*)(SMEM + buf * 8192);
    _Float16* Vlds = (_Float16*)(SMEM + 16384 + buf * 8192);
    _Float16* Bw = (_Float16*)(SMEM + 32768 + buf * 8192 + wave * 2048);
    _Float16* Mw = (_Float16*)(SMEM + 49152 + buf * 8192 + wave * 2048);

#pragma unroll
    for (int hf = 0; hf < 2; hf++) {
      int kcl = hf * 32;
      int R0 = kcl + col, R1 = kcl + 16 + col;
      half8 kf00 = *(const half8*)&Klds[R0 * 64 + ((quad ^ xr) << 3)];
      half8 kf01 = *(const half8*)&Klds[R0 * 64 + (((quad + 4) ^ xr) << 3)];
      half8 kf10 = *(const half8*)&Klds[R1 * 64 + ((quad ^ xr) << 3)];
      half8 kf11 = *(const half8*)&Klds[R1 * 64 + (((quad + 4) ^ xr) << 3)];

      int ku = (kcl >> 3) + quad;
      half8 vf0 = *(const half8*)&Vlds[(0 * 16 + col) * 64 + ((ku ^ xr) << 3)];
      half8 vf1 = *(const half8*)&Vlds[(1 * 16 + col) * 64 + ((ku ^ xr) << 3)];
      half8 vf2 = *(const half8*)&Vlds[(2 * 16 + col) * 64 + ((ku ^ xr) << 3)];
      half8 vf3 = *(const half8*)&Vlds[(3 * 16 + col) * 64 + ((ku ^ xr) << 3)];

      int jm = (kcl >> 3) + (quad >> 1);
      half4 cb0 = *(const half4*)&Bw[col * 64 + ((jm ^ xr) << 3) + (quad & 1) * 4];
      half4 cb1 = *(const half4*)&Bw[col * 64 + (((jm + 2) ^ xr) << 3) + (quad & 1) * 4];
      half4 mk0 = *(const half4*)&Mw[col * 64 + ((jm ^ xr) << 3) + (quad & 1) * 4];
      half4 mk1 = *(const half4*)&Mw[col * 64 + (((jm + 2) ^ xr) << 3) + (quad & 1) * 4];

      // QK^T swapped: S^T[k][q]
      f32x4 s0 = {}, s1 = {};
      s0 = __builtin_amdgcn_mfma_f32_16x16x32_f16(kf00, qf0, s0, 0, 0, 0);
      s0 = __builtin_amdgcn_mfma_f32_16x16x32_f16(kf01, qf1, s0, 0, 0, 0);
      s1 = __builtin_amdgcn_mfma_f32_16x16x32_f16(kf10, qf0, s1, 0, 0, 0);
      s1 = __builtin_amdgcn_mfma_f32_16x16x32_f16(kf11, qf1, s1, 0, 0, 0);

      float x0[4], x1[4];
#pragma unroll
      for (int r = 0; r < 4; r++) {
        x0[r] = s0[r] + (float)cb0[r] + (float)mk0[r];
        x1[r] = s1[r] + (float)cb1[r] + (float)mk1[r];
      }

      float mx = fmaxf(fmaxf(fmaxf(x0[0], x0[1]), fmaxf(x0[2], x0[3])),
                       fmaxf(fmaxf(x1[0], x1[1]), fmaxf(x1[2], x1[3])));
      mx = fmaxf(mx, __shfl_xor(mx, 16));
      mx = fmaxf(mx, __shfl_xor(mx, 32));
      float mnew = fmaxf(m_r, mx);
      float f = __expf(m_r - mnew);
      float p0[4], p1[4];
      float ps = 0.0f;
#pragma unroll
      for (int r = 0; r < 4; r++) {
        p0[r] = __expf(x0[r] - mnew);
        p1[r] = __expf(x1[r] - mnew);
        ps += p0[r] + p1[r];
      }
      ps += __shfl_xor(ps, 16);
      ps += __shfl_xor(ps, 32);
      l_r = l_r * f + ps;
      m_r = mnew;
#pragma unroll
      for (int nt = 0; nt < 4; nt++) acc[nt] *= f;

      half2_t c0 = {(_Float16)p0[0], (_Float16)p0[1]};
      half2_t c1 = {(_Float16)p0[2], (_Float16)p0[3]};
      half2_t c2 = {(_Float16)p1[0], (_Float16)p1[1]};
      half2_t c3 = {(_Float16)p1[2], (_Float16)p1[3]};
      P2[wave][col][quad * 2 + 0] = __builtin_bit_cast(unsigned, c0);
      P2[wave][col][quad * 2 + 1] = __builtin_bit_cast(unsigned, c1);
      P2[wave][col][8 + quad * 2 + 0] = __builtin_bit_cast(unsigned, c2);
      P2[wave][col][8 + quad * 2 + 1] = __builtin_bit_cast(unsigned, c3);

      half8 pf = *(const half8*)&P2[wave][col][quad * 4];

      acc[0] = __builtin_amdgcn_mfma_f32_16x16x32_f16(vf0, pf, acc[0], 0, 0, 0);
      acc[1] = __builtin_amdgcn_mfma_f32_16x16x32_f16(vf1, pf, acc[1], 0, 0, 0);
      acc[2] = __builtin_amdgcn_mfma_f32_16x16x32_f16(vf2, pf, acc[2], 0, 0, 0);
      acc[3] = __builtin_amdgcn_mfma_f32_16x16x32_f16(vf3, pf, acc[3], 0, 0, 0);
    }
    __builtin_amdgcn_s_barrier();  // no wave overwrites buf t&1 until all done
  }
  asm volatile("s_waitcnt vmcnt(0)" ::: "memory");

  // ---- epilogue: normalize and write ----
  float linv = 1.0f / l_r;
  _Float16* aop = ao + (size_t)(b * S_ + q) * HIDDEN + h * DK;
#pragma unroll
  for (int nt = 0; nt < 4; nt++)
#pragma unroll
    for (int rp = 0; rp < 2; rp++) {
      int d = nt * 16 + quad * 4 + rp * 2;
      half2_t o = {(_Float16)(acc[nt][rp * 2] * linv),
                   (_Float16)(acc[nt][rp * 2 + 1] * linv)};
      *(half2_t*)(aop + d) = o;
    }
}

// ---------------- output projection v2: staged-GEMM template ----------------
__global__ __launch_bounds__(256) void out_proj2(
    const _Float16* __restrict__ ao, const _Float16* __restrict__ wo,
    const float* __restrict__ bo, float* __restrict__ out) {
  int m0 = blockIdx.x * 64;
  int n0 = blockIdx.y * 64;
  int tid = threadIdx.x, wave = tid >> 6, lane = tid & 63;
  int r16 = lane & 15, quad = lane >> 4;

  __shared__ __align__(16) char SM[16384];
  int rl = lane >> 2;
  int ku = lane & 3;
  int kup = ku ^ ((rl >> 1) & 3);

  const _Float16* Xg = ao + (size_t)(m0 + wave * 16 + rl) * HIDDEN + kup * 8;
  const _Float16* Wg = wo + (size_t)(n0 + wave * 16 + rl) * HIDDEN + kup * 8;

  auto stage = [&](int k0, int buf) __attribute__((always_inline)) {
    gload16(Xg + k0, SM + buf * 4096 + wave * 1024);
    gload16(Wg + k0, SM + 8192 + buf * 4096 + wave * 1024);
  };

  f32x4 acc[4] = {};
  stage(0, 0);
  int sw = (r16 >> 1) & 3;

  for (int t = 0; t < 16; t++) {
    int k0n = (t < 15) ? (t + 1) * 32 : 0;
    stage(k0n, (t + 1) & 1);
    asm volatile("s_waitcnt vmcnt(2)" ::: "memory");
    __builtin_amdgcn_sched_barrier(0);
    __builtin_amdgcn_s_barrier();

    int buf = t & 1;
    const _Float16* XT = (const _Float16*)(SM + buf * 4096);
    const _Float16* WT = (const _Float16*)(SM + 8192 + buf * 4096);
    half8 a = *(const half8*)&XT[(wave * 16 + r16) * 32 + ((quad ^ sw) << 3)];
#pragma unroll
    for (int nt = 0; nt < 4; nt++) {
      half8 bfr = *(const half8*)&WT[(nt * 16 + r16) * 32 + ((quad ^ sw) << 3)];
      acc[nt] = __builtin_amdgcn_mfma_f32_16x16x32_f16(a, bfr, acc[nt], 0, 0, 0);
    }
    __builtin_amdgcn_s_barrier();
  }
  asm volatile("s_waitcnt vmcnt(0)" ::: "memory");

#pragma unroll
  for (int nt = 0; nt < 4; nt++) {
    int gcol = n0 + nt * 16 + r16;
    float bv_ = bo[gcol];
#pragma unroll
    for (int r = 0; r < 4; r++) {
      int grow = m0 + wave * 16 + quad * 4 + r;
      out[grow * HIDDEN + gcol] = acc[nt][r] + bv_;
    }
  }
}

// ---------------- launch ----------------
extern "C" void kernel_launch(void* const* d_in, const int* in_sizes, int n_in,
                              void* d_out, int out_size, void* d_ws, size_t ws_size,
                              hipStream_t stream) {
  const float* q = (const float*)d_in[0];
  const float* k = (const float*)d_in[1];
  const float* v = (const float*)d_in[2];
  const float* attn_bias = (const float*)d_in[3];
  const int* gmask = (const int*)d_in[4];
  const float* subsq = (const float*)d_in[5];
  const float* Wq = (const float*)d_in[6];
  const float* bq = (const float*)d_in[7];
  const float* Wk = (const float*)d_in[8];
  const float* bk = (const float*)d_in[9];
  const float* Wv = (const float*)d_in[10];
  const float* bv = (const float*)d_in[11];
  const float* Wo = (const float*)d_in[12];
  const float* bo = (const float*)d_in[13];

  char* ws = (char*)d_ws;
  _Float16* msk16 = (_Float16*)(ws + 0);          // 8 MB, row layout
  _Float16* cb16 = (_Float16*)(ws + 8388608);     // 64 MB, streaming tiles
  _Float16* wq16 = (_Float16*)(ws + 75497472);
  _Float16* wk16 = (_Float16*)(ws + 76021760);
  _Float16* wv16 = (_Float16*)(ws + 76546048);
  _Float16* wo16 = (_Float16*)(ws + 77070336);
  _Float16* qhb = (_Float16*)(ws + 77594624);
  _Float16* khb = (_Float16*)(ws + 81788928);
  _Float16* vtb = (_Float16*)(ws + 85983232);
  _Float16* aob = (_Float16*)(ws + 90177536);

  fusemask<<<dim3(4096), 256, 0, stream>>>(gmask, subsq, msk16);
  cvt4<<<dim3(256, 4), 256, 0, stream>>>(Wq, Wk, Wv, Wo, wq16, wk16, wv16, wo16);
  repack_bias<<<dim3(2048), 256, 0, stream>>>(attn_bias, cb16);
  proj_qkv3<<<dim3(64, 24), 256, 0, stream>>>(q, k, v, wq16, wk16, wv16,
                                              bq, bk, bv, qhb, khb, vtb);
  attn14<<<dim3(512), 256, 0, stream>>>(qhb, khb, vtb, cb16, msk16, aob);
  out_proj2<<<dim3(64, 8), 256, 0, stream>>>(aob, wo16, bo, (float*)d_out);
}

// Round 16
// 85.704 us; speedup vs baseline: 1.3194x; 1.3194x over previous
//
#include <hip/hip_runtime.h>

#define HIDDEN 512
#define HEADS 8
#define DK 64
#define S_ 1024
#define NEGV -1000000000.0f

typedef _Float16 half8 __attribute__((ext_vector_type(8)));
typedef _Float16 half4 __attribute__((ext_vector_type(4)));
typedef _Float16 half2_t __attribute__((ext_vector_type(2)));
typedef float f32x4 __attribute__((ext_vector_type(4)));
typedef float f32x2 __attribute__((ext_vector_type(2)));
typedef int i32x4 __attribute__((ext_vector_type(4)));

// async global->LDS, 16B/lane: LDS dest = uniform base + lane*16 (linear);
// global src is per-lane (used for gather + bank-deswizzle).
__device__ __forceinline__ void gload16(const void* g, void* l) {
  __builtin_amdgcn_global_load_lds(
      (const __attribute__((address_space(1))) unsigned int*)g,
      (__attribute__((address_space(3))) unsigned int*)l, 16, 0, 0);
}

// ---------------- weights fp32 -> fp16 ----------------
__global__ __launch_bounds__(256) void cvt4(const float* __restrict__ a0,
                                            const float* __restrict__ a1,
                                            const float* __restrict__ a2,
                                            const float* __restrict__ a3,
                                            _Float16* o0, _Float16* o1, _Float16* o2, _Float16* o3) {
  const float* src = blockIdx.y == 0 ? a0 : (blockIdx.y == 1 ? a1 : (blockIdx.y == 2 ? a2 : a3));
  _Float16* dst = blockIdx.y == 0 ? o0 : (blockIdx.y == 1 ? o1 : (blockIdx.y == 2 ? o2 : o3));
  int i = (blockIdx.x * 256 + threadIdx.x) * 4;
  float4 v = *(const float4*)(src + i);
  half4 h = {(_Float16)v.x, (_Float16)v.y, (_Float16)v.z, (_Float16)v.w};
  *(half4*)(dst + i) = h;
}

// ---------------- fuse gmask+subsq -> fp16 (row layout) ----------------
__global__ __launch_bounds__(256) void fusemask(const int* __restrict__ gm,
                                                const float* __restrict__ sq,
                                                _Float16* __restrict__ msk) {
  int i = (blockIdx.x * 256 + threadIdx.x) * 4;
  i32x4 g = *(const i32x4*)(gm + i);
  f32x4 s = *(const f32x4*)(sq + i);
  half4 o;
#pragma unroll
  for (int j = 0; j < 4; j++)
    o[j] = (_Float16)(g[j] == 0 ? -30000.0f : s[j]);
  *(half4*)(msk + i) = o;
}

// ---------------- QKV projection v3: fp32 X staged via gload16, fp16 W ----------------
// (validated in R15 at absmax 9.8e-4) — drops the cvt3 pass entirely.
__global__ __launch_bounds__(256) void proj_qkv3(
    const float* __restrict__ qf, const float* __restrict__ kf,
    const float* __restrict__ vf,
    const _Float16* __restrict__ wq, const _Float16* __restrict__ wk,
    const _Float16* __restrict__ wv,
    const float* __restrict__ bq, const float* __restrict__ bk,
    const float* __restrict__ bv,
    _Float16* __restrict__ qh, _Float16* __restrict__ kh, _Float16* __restrict__ vt) {
  int m0 = blockIdx.x * 64;
  int nb = blockIdx.y;
  int which = nb >> 3;
  int n0 = (nb & 7) * 64;
  const float* X = which == 0 ? qf : (which == 1 ? kf : vf);
  const _Float16* W = which == 0 ? wq : (which == 1 ? wk : wv);
  const float* bias = which == 0 ? bq : (which == 1 ? bk : bv);

  int tid = threadIdx.x;
  int wave = tid >> 6, lane = tid & 63;
  int r16 = lane & 15, quad = lane >> 4;

  // LDS: X dbuf 2x8K [0,16384) | W dbuf 2x4K [16384,24576) | T 9216 [24576,..)
  __shared__ __align__(16) char SM[33792];
  _Float16(*T)[72] = (_Float16(*)[72])(SM + 24576);

  int xrow = lane >> 3;            // 0..7
  int xu = (lane & 7) ^ xrow;      // pre-swizzled logical unit
  int rl = lane >> 2;
  int ku = lane & 3;
  int kup = ku ^ ((rl >> 1) & 3);

  const float* Xg0 = X + (size_t)(m0 + wave * 16 + xrow) * HIDDEN + xu * 4;
  const float* Xg1 = X + (size_t)(m0 + wave * 16 + 8 + xrow) * HIDDEN + xu * 4;
  const _Float16* Wg = W + (size_t)(n0 + wave * 16 + rl) * HIDDEN + kup * 8;

  auto stage = [&](int k0, int buf) __attribute__((always_inline)) {
    gload16(Xg0 + k0, SM + buf * 8192 + wave * 2048);
    gload16(Xg1 + k0, SM + buf * 8192 + wave * 2048 + 1024);
    gload16(Wg + k0, SM + 16384 + buf * 4096 + wave * 1024);
  };

  f32x4 acc[4] = {};
  stage(0, 0);
  int sw = (r16 >> 1) & 3;
  int xk = r16 & 7;  // X read swizzle key

  for (int t = 0; t < 16; t++) {
    int k0n = (t < 15) ? (t + 1) * 32 : 0;
    stage(k0n, (t + 1) & 1);
    asm volatile("s_waitcnt vmcnt(3)" ::: "memory");
    __builtin_amdgcn_sched_barrier(0);
    __builtin_amdgcn_s_barrier();

    int buf = t & 1;
    const float* XT = (const float*)(SM + buf * 8192 + wave * 2048);
    const _Float16* WT = (const _Float16*)(SM + 16384 + buf * 4096);
    f32x4 lo = *(const f32x4*)&XT[r16 * 32 + (((2 * quad) ^ xk) << 2)];
    f32x4 hi = *(const f32x4*)&XT[r16 * 32 + (((2 * quad + 1) ^ xk) << 2)];
    half8 a = {(_Float16)lo[0], (_Float16)lo[1], (_Float16)lo[2], (_Float16)lo[3],
               (_Float16)hi[0], (_Float16)hi[1], (_Float16)hi[2], (_Float16)hi[3]};
#pragma unroll
    for (int nt = 0; nt < 4; nt++) {
      half8 bfr = *(const half8*)&WT[(nt * 16 + r16) * 32 + ((quad ^ sw) << 3)];
      acc[nt] = __builtin_amdgcn_mfma_f32_16x16x32_f16(a, bfr, acc[nt], 0, 0, 0);
    }
    __builtin_amdgcn_s_barrier();
  }
  asm volatile("s_waitcnt vmcnt(0)" ::: "memory");

  if (which < 2) {
    _Float16* OUT = which == 0 ? qh : kh;
    float scale = which == 0 ? 0.125f : 1.0f;
#pragma unroll
    for (int nt = 0; nt < 4; nt++) {
      int gcol = n0 + nt * 16 + r16;
      float bv_ = bias[gcol];
      int h = gcol >> 6, d = gcol & 63;
#pragma unroll
      for (int r = 0; r < 4; r++) {
        int grow = m0 + wave * 16 + quad * 4 + r;
        int bb = grow >> 10, s = grow & 1023;
        float val = (acc[nt][r] + bv_) * scale;
        OUT[((bb * HEADS + h) * S_ + s) * DK + d] = (_Float16)val;
      }
    }
  } else {
#pragma unroll
    for (int nt = 0; nt < 4; nt++) {
      int lc = nt * 16 + r16;
      float bv_ = bias[n0 + lc];
#pragma unroll
      for (int r = 0; r < 4; r++) {
        int lr = wave * 16 + quad * 4 + r;
        T[lr][lc] = (_Float16)(acc[nt][r] + bv_);
      }
    }
    __syncthreads();
    int dl = tid >> 2;
    int s4 = (tid & 3) * 16;
    _Float16 tmp[16];
#pragma unroll
    for (int i = 0; i < 16; i++) tmp[i] = T[s4 + i][dl];
    int h = n0 >> 6;
    int bb = m0 >> 10;
    int s0 = m0 & 1023;
    _Float16* p = vt + ((bb * HEADS + h) * DK + dl) * S_ + s0 + s4;
    *(half8*)(p) = *(half8*)(tmp);
    *(half8*)(p + 8) = *(half8*)(tmp + 8);
  }
}

// ---------------- attention v13 (verbatim R14 best): 8-wave dbuf clump pipeline ----------------
__global__ __launch_bounds__(512) void attn13(
    const _Float16* __restrict__ qh, const _Float16* __restrict__ kh,
    const _Float16* __restrict__ vt,
    const float* __restrict__ attn_bias, const _Float16* __restrict__ msk,
    _Float16* __restrict__ ao) {
  int id = blockIdx.x;
  int bh = (((id >> 3) & 3) << 3) | (id & 7);  // bh&7 == dispatch xcd
  int qtile = id >> 5;                         // 0..7 (128 q-rows each)
  int b = bh >> 3, h = bh & 7;
  int tid = threadIdx.x;
  int wave = tid >> 6, lane = tid & 63;
  int col = lane & 15, quad = lane >> 4;
  int q0w = qtile * 128 + wave * 16;
  int q = q0w + col;
  int xr = col & 7;
  int lr8 = lane >> 3;
  int u8 = (lane & 7) ^ lr8;

  __shared__ __align__(16) char SMEM[141312];
  unsigned(*P2)[16][20] = (unsigned(*)[16][20])(SMEM + 131072);

  const _Float16* Q = qh + ((size_t)bh * S_ + q) * DK;
  const _Float16* K = kh + (size_t)bh * S_ * DK;
  const _Float16* V = vt + (size_t)bh * DK * S_;
  const float* BIrow = attn_bias + ((size_t)bh * S_ + q0w) * S_;
  const _Float16* MSrow = msk + ((size_t)b * S_ + q0w) * S_;

  half8 qf0 = *(const half8*)(Q + quad * 8);
  half8 qf1 = *(const half8*)(Q + 32 + quad * 8);

  f32x4 acc[4] = {};
  float m_r = -1e38f, l_r = 0.0f;

  auto stage_clump = [&](int tt, int buf) __attribute__((always_inline)) {
    int kb = tt * 64;
    {
      int row = wave * 8 + lr8;
      gload16(K + (size_t)(kb + row) * DK + u8 * 8,
              SMEM + buf * 8192 + wave * 1024);
      gload16(V + (size_t)row * S_ + kb + u8 * 8,
              SMEM + 16384 + buf * 8192 + wave * 1024);
    }
#pragma unroll
    for (int c = 0; c < 4; c++) {
      int row = c * 4 + (lane >> 4);
      int ju = (lane & 15) ^ (row & 7);
      gload16(BIrow + (size_t)row * S_ + kb + ju * 4,
              SMEM + 32768 + buf * 32768 + wave * 4096 + c * 1024);
    }
#pragma unroll
    for (int c = 0; c < 2; c++) {
      int row = c * 8 + lr8;
      gload16(MSrow + (size_t)row * S_ + kb + u8 * 8,
              SMEM + 98304 + buf * 16384 + wave * 2048 + c * 1024);
    }
  };

  stage_clump(0, 0);

  for (int t = 0; t < 16; t++) {
    stage_clump((t + 1) & 15, (t + 1) & 1);

    asm volatile("s_waitcnt vmcnt(8)" ::: "memory");
    __builtin_amdgcn_sched_barrier(0);
    __builtin_amdgcn_s_barrier();

    int buf = t & 1;
    _Float16* Klds = (_Float16*)(SMEM + buf * 8192);
    _Float16* Vlds = (_Float16*)(SMEM + 16384 + buf * 8192);
    float* Bw = (float*)(SMEM + 32768 + buf * 32768 + wave * 4096);
    _Float16* Mw = (_Float16*)(SMEM + 98304 + buf * 16384 + wave * 2048);

#pragma unroll
    for (int hf = 0; hf < 2; hf++) {
      int kcl = hf * 32;
      int R0 = kcl + col, R1 = kcl + 16 + col;
      half8 kf00 = *(const half8*)&Klds[R0 * 64 + ((quad ^ xr) << 3)];
      half8 kf01 = *(const half8*)&Klds[R0 * 64 + (((quad + 4) ^ xr) << 3)];
      half8 kf10 = *(const half8*)&Klds[R1 * 64 + ((quad ^ xr) << 3)];
      half8 kf11 = *(const half8*)&Klds[R1 * 64 + (((quad + 4) ^ xr) << 3)];

      int ku = (kcl >> 3) + quad;
      half8 vf0 = *(const half8*)&Vlds[(0 * 16 + col) * 64 + ((ku ^ xr) << 3)];
      half8 vf1 = *(const half8*)&Vlds[(1 * 16 + col) * 64 + ((ku ^ xr) << 3)];
      half8 vf2 = *(const half8*)&Vlds[(2 * 16 + col) * 64 + ((ku ^ xr) << 3)];
      half8 vf3 = *(const half8*)&Vlds[(3 * 16 + col) * 64 + ((ku ^ xr) << 3)];

      int jb = kcl >> 2;
      f32x4 bi0 = *(const f32x4*)&Bw[col * 64 + (((jb + quad) ^ xr) << 2)];
      f32x4 bi1 = *(const f32x4*)&Bw[col * 64 + (((jb + 4 + quad) ^ xr) << 2)];
      int jm = (kcl >> 3) + (quad >> 1);
      half4 mk0 = *(const half4*)&Mw[col * 64 + ((jm ^ xr) << 3) + (quad & 1) * 4];
      half4 mk1 = *(const half4*)&Mw[col * 64 + (((jm + 2) ^ xr) << 3) + (quad & 1) * 4];

      f32x4 s0 = {}, s1 = {};
      s0 = __builtin_amdgcn_mfma_f32_16x16x32_f16(kf00, qf0, s0, 0, 0, 0);
      s0 = __builtin_amdgcn_mfma_f32_16x16x32_f16(kf01, qf1, s0, 0, 0, 0);
      s1 = __builtin_amdgcn_mfma_f32_16x16x32_f16(kf10, qf0, s1, 0, 0, 0);
      s1 = __builtin_amdgcn_mfma_f32_16x16x32_f16(kf11, qf1, s1, 0, 0, 0);

      float x0[4], x1[4];
#pragma unroll
      for (int r = 0; r < 4; r++) {
        x0[r] = s0[r] + bi0[r] + (float)mk0[r];
        x1[r] = s1[r] + bi1[r] + (float)mk1[r];
      }

      float mx = fmaxf(fmaxf(fmaxf(x0[0], x0[1]), fmaxf(x0[2], x0[3])),
                       fmaxf(fmaxf(x1[0], x1[1]), fmaxf(x1[2], x1[3])));
      mx = fmaxf(mx, __shfl_xor(mx, 16));
      mx = fmaxf(mx, __shfl_xor(mx, 32));
      float mnew = fmaxf(m_r, mx);
      float f = __expf(m_r - mnew);
      float p0[4], p1[4];
      float ps = 0.0f;
#pragma unroll
      for (int r = 0; r < 4; r++) {
        p0[r] = __expf(x0[r] - mnew);
        p1[r] = __expf(x1[r] - mnew);
        ps += p0[r] + p1[r];
      }
      ps += __shfl_xor(ps, 16);
      ps += __shfl_xor(ps, 32);
      l_r = l_r * f + ps;
      m_r = mnew;
#pragma unroll
      for (int nt = 0; nt < 4; nt++) acc[nt] *= f;

      half2_t c0 = {(_Float16)p0[0], (_Float16)p0[1]};
      half2_t c1 = {(_Float16)p0[2], (_Float16)p0[3]};
      half2_t c2 = {(_Float16)p1[0], (_Float16)p1[1]};
      half2_t c3 = {(_Float16)p1[2], (_Float16)p1[3]};
      P2[wave][col][quad * 2 + 0] = __builtin_bit_cast(unsigned, c0);
      P2[wave][col][quad * 2 + 1] = __builtin_bit_cast(unsigned, c1);
      P2[wave][col][8 + quad * 2 + 0] = __builtin_bit_cast(unsigned, c2);
      P2[wave][col][8 + quad * 2 + 1] = __builtin_bit_cast(unsigned, c3);

      half8 pf = *(const half8*)&P2[wave][col][quad * 4];

      acc[0] = __builtin_amdgcn_mfma_f32_16x16x32_f16(vf0, pf, acc[0], 0, 0, 0);
      acc[1] = __builtin_amdgcn_mfma_f32_16x16x32_f16(vf1, pf, acc[1], 0, 0, 0);
      acc[2] = __builtin_amdgcn_mfma_f32_16x16x32_f16(vf2, pf, acc[2], 0, 0, 0);
      acc[3] = __builtin_amdgcn_mfma_f32_16x16x32_f16(vf3, pf, acc[3], 0, 0, 0);
    }
    __builtin_amdgcn_s_barrier();
  }
  asm volatile("s_waitcnt vmcnt(0)" ::: "memory");

  float linv = 1.0f / l_r;
  _Float16* aop = ao + (size_t)(b * S_ + q) * HIDDEN + h * DK;
#pragma unroll
  for (int nt = 0; nt < 4; nt++)
#pragma unroll
    for (int rp = 0; rp < 2; rp++) {
      int d = nt * 16 + quad * 4 + rp * 2;
      half2_t o = {(_Float16)(acc[nt][rp * 2] * linv),
                   (_Float16)(acc[nt][rp * 2 + 1] * linv)};
      *(half2_t*)(aop + d) = o;
    }
}

// ---------------- output projection v2: staged-GEMM template ----------------
__global__ __launch_bounds__(256) void out_proj2(
    const _Float16* __restrict__ ao, const _Float16* __restrict__ wo,
    const float* __restrict__ bo, float* __restrict__ out) {
  int m0 = blockIdx.x * 64;
  int n0 = blockIdx.y * 64;
  int tid = threadIdx.x, wave = tid >> 6, lane = tid & 63;
  int r16 = lane & 15, quad = lane >> 4;

  __shared__ __align__(16) char SM[16384];
  int rl = lane >> 2;
  int ku = lane & 3;
  int kup = ku ^ ((rl >> 1) & 3);

  const _Float16* Xg = ao + (size_t)(m0 + wave * 16 + rl) * HIDDEN + kup * 8;
  const _Float16* Wg = wo + (size_t)(n0 + wave * 16 + rl) * HIDDEN + kup * 8;

  auto stage = [&](int k0, int buf) __attribute__((always_inline)) {
    gload16(Xg + k0, SM + buf * 4096 + wave * 1024);
    gload16(Wg + k0, SM + 8192 + buf * 4096 + wave * 1024);
  };

  f32x4 acc[4] = {};
  stage(0, 0);
  int sw = (r16 >> 1) & 3;

  for (int t = 0; t < 16; t++) {
    int k0n = (t < 15) ? (t + 1) * 32 : 0;
    stage(k0n, (t + 1) & 1);
    asm volatile("s_waitcnt vmcnt(2)" ::: "memory");
    __builtin_amdgcn_sched_barrier(0);
    __builtin_amdgcn_s_barrier();

    int buf = t & 1;
    const _Float16* XT = (const _Float16*)(SM + buf * 4096);
    const _Float16* WT = (const _Float16*)(SM + 8192 + buf * 4096);
    half8 a = *(const half8*)&XT[(wave * 16 + r16) * 32 + ((quad ^ sw) << 3)];
#pragma unroll
    for (int nt = 0; nt < 4; nt++) {
      half8 bfr = *(const half8*)&WT[(nt * 16 + r16) * 32 + ((quad ^ sw) << 3)];
      acc[nt] = __builtin_amdgcn_mfma_f32_16x16x32_f16(a, bfr, acc[nt], 0, 0, 0);
    }
    __builtin_amdgcn_s_barrier();
  }
  asm volatile("s_waitcnt vmcnt(0)" ::: "memory");

#pragma unroll
  for (int nt = 0; nt < 4; nt++) {
    int gcol = n0 + nt * 16 + r16;
    float bv_ = bo[gcol];
#pragma unroll
    for (int r = 0; r < 4; r++) {
      int grow = m0 + wave * 16 + quad * 4 + r;
      out[grow * HIDDEN + gcol] = acc[nt][r] + bv_;
    }
  }
}

// ---------------- launch ----------------
extern "C" void kernel_launch(void* const* d_in, const int* in_sizes, int n_in,
                              void* d_out, int out_size, void* d_ws, size_t ws_size,
                              hipStream_t stream) {
  const float* q = (const float*)d_in[0];
  const float* k = (const float*)d_in[1];
  const float* v = (const float*)d_in[2];
  const float* attn_bias = (const float*)d_in[3];
  const int* gmask = (const int*)d_in[4];
  const float* subsq = (const float*)d_in[5];
  const float* Wq = (const float*)d_in[6];
  const float* bq = (const float*)d_in[7];
  const float* Wk = (const float*)d_in[8];
  const float* bk = (const float*)d_in[9];
  const float* Wv = (const float*)d_in[10];
  const float* bv = (const float*)d_in[11];
  const float* Wo = (const float*)d_in[12];
  const float* bo = (const float*)d_in[13];

  char* ws = (char*)d_ws;
  _Float16* msk16 = (_Float16*)(ws + 0);  // 8 MB
  _Float16* wq16 = (_Float16*)(ws + 12582912);
  _Float16* wk16 = (_Float16*)(ws + 13107200);
  _Float16* wv16 = (_Float16*)(ws + 13631488);
  _Float16* wo16 = (_Float16*)(ws + 14155776);
  _Float16* qhb = (_Float16*)(ws + 14680064);
  _Float16* khb = (_Float16*)(ws + 18874368);
  _Float16* vtb = (_Float16*)(ws + 23068672);
  _Float16* aob = (_Float16*)(ws + 27262976);

  fusemask<<<dim3(4096), 256, 0, stream>>>(gmask, subsq, msk16);
  cvt4<<<dim3(256, 4), 256, 0, stream>>>(Wq, Wk, Wv, Wo, wq16, wk16, wv16, wo16);
  proj_qkv3<<<dim3(64, 24), 256, 0, stream>>>(q, k, v, wq16, wk16, wv16,
                                              bq, bk, bv, qhb, khb, vtb);
  attn13<<<dim3(256), 512, 0, stream>>>(qhb, khb, vtb, attn_bias, msk16, aob);
  out_proj2<<<dim3(64, 8), 256, 0, stream>>>(aob, wo16, bo, (float*)d_out);
}

// Round 17
// 78.996 us; speedup vs baseline: 1.4314x; 1.0849x over previous
//
#include <hip/hip_runtime.h>

#define HIDDEN 512
#define HEADS 8
#define DK 64
#define S_ 1024
#define NEGV -1000000000.0f

typedef _Float16 half8 __attribute__((ext_vector_type(8)));
typedef _Float16 half4 __attribute__((ext_vector_type(4)));
typedef _Float16 half2_t __attribute__((ext_vector_type(2)));
typedef float f32x4 __attribute__((ext_vector_type(4)));
typedef float f32x2 __attribute__((ext_vector_type(2)));
typedef int i32x4 __attribute__((ext_vector_type(4)));

// async global->LDS, 16B/lane: LDS dest = uniform base + lane*16 (linear);
// global src is per-lane (used for gather + bank-deswizzle).
__device__ __forceinline__ void gload16(const void* g, void* l) {
  __builtin_amdgcn_global_load_lds(
      (const __attribute__((address_space(1))) unsigned int*)g,
      (__attribute__((address_space(3))) unsigned int*)l, 16, 0, 0);
}

// ---------------- fused prep: q/k/v cvt + weights cvt + mask fusion ----------------
// blocks [0,6144): q/k/v fp32->fp16 (2048 each)
// blocks [6144,7168): weights (256 each of Wq,Wk,Wv,Wo)
// blocks [7168,11264): fusemask (4096)
__global__ __launch_bounds__(256) void prep(
    const float* __restrict__ q, const float* __restrict__ k,
    const float* __restrict__ v,
    const float* __restrict__ Wq, const float* __restrict__ Wk,
    const float* __restrict__ Wv, const float* __restrict__ Wo,
    const int* __restrict__ gm, const float* __restrict__ sq,
    _Float16* q16, _Float16* k16, _Float16* v16,
    _Float16* wq16, _Float16* wk16, _Float16* wv16, _Float16* wo16,
    _Float16* msk) {
  int blk = blockIdx.x;
  if (blk < 6144) {
    int job = blk / 2048, rel = blk % 2048;
    const float* src = job == 0 ? q : (job == 1 ? k : v);
    _Float16* dst = job == 0 ? q16 : (job == 1 ? k16 : v16);
    int i = (rel * 256 + threadIdx.x) * 4;
    float4 vv = *(const float4*)(src + i);
    half4 h = {(_Float16)vv.x, (_Float16)vv.y, (_Float16)vv.z, (_Float16)vv.w};
    *(half4*)(dst + i) = h;
  } else if (blk < 7168) {
    int job = (blk - 6144) / 256, rel = (blk - 6144) % 256;
    const float* src = job == 0 ? Wq : (job == 1 ? Wk : (job == 2 ? Wv : Wo));
    _Float16* dst = job == 0 ? wq16 : (job == 1 ? wk16 : (job == 2 ? wv16 : wo16));
    int i = (rel * 256 + threadIdx.x) * 4;
    float4 vv = *(const float4*)(src + i);
    half4 h = {(_Float16)vv.x, (_Float16)vv.y, (_Float16)vv.z, (_Float16)vv.w};
    *(half4*)(dst + i) = h;
  } else {
    int rel = blk - 7168;
    int i = (rel * 256 + threadIdx.x) * 4;
    i32x4 g = *(const i32x4*)(gm + i);
    f32x4 s = *(const f32x4*)(sq + i);
    half4 o;
#pragma unroll
    for (int j = 0; j < 4; j++)
      o[j] = (_Float16)(g[j] == 0 ? -30000.0f : s[j]);
    *(half4*)(msk + i) = o;
  }
}

// ---------------- QKV projection v2 (R12/R14-proven): clump-pipelined staged GEMM ----------------
__global__ __launch_bounds__(256) void proj_qkv2(
    const _Float16* __restrict__ q16, const _Float16* __restrict__ k16,
    const _Float16* __restrict__ v16,
    const _Float16* __restrict__ wq, const _Float16* __restrict__ wk,
    const _Float16* __restrict__ wv,
    const float* __restrict__ bq, const float* __restrict__ bk,
    const float* __restrict__ bv,
    _Float16* __restrict__ qh, _Float16* __restrict__ kh, _Float16* __restrict__ vt) {
  int m0 = blockIdx.x * 64;
  int nb = blockIdx.y;
  int which = nb >> 3;
  int n0 = (nb & 7) * 64;
  const _Float16* X = which == 0 ? q16 : (which == 1 ? k16 : v16);
  const _Float16* W = which == 0 ? wq : (which == 1 ? wk : wv);
  const float* bias = which == 0 ? bq : (which == 1 ? bk : bv);

  int tid = threadIdx.x;
  int wave = tid >> 6, lane = tid & 63;
  int r16 = lane & 15, quad = lane >> 4;

  __shared__ __align__(16) char SM[25600];
  _Float16(*T)[72] = (_Float16(*)[72])(SM + 16384);

  int rl = lane >> 2;
  int ku = lane & 3;
  int kup = ku ^ ((rl >> 1) & 3);

  const _Float16* Xg = X + (size_t)(m0 + wave * 16 + rl) * HIDDEN + kup * 8;
  const _Float16* Wg = W + (size_t)(n0 + wave * 16 + rl) * HIDDEN + kup * 8;

  auto stage = [&](int k0, int buf) __attribute__((always_inline)) {
    gload16(Xg + k0, SM + buf * 4096 + wave * 1024);
    gload16(Wg + k0, SM + 8192 + buf * 4096 + wave * 1024);
  };

  f32x4 acc[4] = {};
  stage(0, 0);
  int sw = (r16 >> 1) & 3;

  for (int t = 0; t < 16; t++) {
    int k0n = (t < 15) ? (t + 1) * 32 : 0;
    stage(k0n, (t + 1) & 1);
    asm volatile("s_waitcnt vmcnt(2)" ::: "memory");
    __builtin_amdgcn_sched_barrier(0);
    __builtin_amdgcn_s_barrier();

    int buf = t & 1;
    const _Float16* XT = (const _Float16*)(SM + buf * 4096);
    const _Float16* WT = (const _Float16*)(SM + 8192 + buf * 4096);
    half8 a = *(const half8*)&XT[(wave * 16 + r16) * 32 + ((quad ^ sw) << 3)];
#pragma unroll
    for (int nt = 0; nt < 4; nt++) {
      half8 bfr = *(const half8*)&WT[(nt * 16 + r16) * 32 + ((quad ^ sw) << 3)];
      acc[nt] = __builtin_amdgcn_mfma_f32_16x16x32_f16(a, bfr, acc[nt], 0, 0, 0);
    }
    __builtin_amdgcn_s_barrier();
  }
  asm volatile("s_waitcnt vmcnt(0)" ::: "memory");

  if (which < 2) {
    _Float16* OUT = which == 0 ? qh : kh;
    float scale = which == 0 ? 0.125f : 1.0f;
#pragma unroll
    for (int nt = 0; nt < 4; nt++) {
      int gcol = n0 + nt * 16 + r16;
      float bv_ = bias[gcol];
      int h = gcol >> 6, d = gcol & 63;
#pragma unroll
      for (int r = 0; r < 4; r++) {
        int grow = m0 + wave * 16 + quad * 4 + r;
        int bb = grow >> 10, s = grow & 1023;
        float val = (acc[nt][r] + bv_) * scale;
        OUT[((bb * HEADS + h) * S_ + s) * DK + d] = (_Float16)val;
      }
    }
  } else {
#pragma unroll
    for (int nt = 0; nt < 4; nt++) {
      int lc = nt * 16 + r16;
      float bv_ = bias[n0 + lc];
#pragma unroll
      for (int r = 0; r < 4; r++) {
        int lr = wave * 16 + quad * 4 + r;
        T[lr][lc] = (_Float16)(acc[nt][r] + bv_);
      }
    }
    __syncthreads();
    int dl = tid >> 2;
    int s4 = (tid & 3) * 16;
    _Float16 tmp[16];
#pragma unroll
    for (int i = 0; i < 16; i++) tmp[i] = T[s4 + i][dl];
    int h = n0 >> 6;
    int bb = m0 >> 10;
    int s0 = m0 & 1023;
    _Float16* p = vt + ((bb * HEADS + h) * DK + dl) * S_ + s0 + s4;
    *(half8*)(p) = *(half8*)(tmp);
    *(half8*)(p + 8) = *(half8*)(tmp + 8);
  }
}

// ---------------- attention v13 + T5 setprio: 8-wave dbuf clump pipeline ----------------
__global__ __launch_bounds__(512) void attn13(
    const _Float16* __restrict__ qh, const _Float16* __restrict__ kh,
    const _Float16* __restrict__ vt,
    const float* __restrict__ attn_bias, const _Float16* __restrict__ msk,
    _Float16* __restrict__ ao) {
  int id = blockIdx.x;
  int bh = (((id >> 3) & 3) << 3) | (id & 7);  // bh&7 == dispatch xcd
  int qtile = id >> 5;                         // 0..7 (128 q-rows each)
  int b = bh >> 3, h = bh & 7;
  int tid = threadIdx.x;
  int wave = tid >> 6, lane = tid & 63;
  int col = lane & 15, quad = lane >> 4;
  int q0w = qtile * 128 + wave * 16;
  int q = q0w + col;
  int xr = col & 7;
  int lr8 = lane >> 3;
  int u8 = (lane & 7) ^ lr8;

  __shared__ __align__(16) char SMEM[141312];
  unsigned(*P2)[16][20] = (unsigned(*)[16][20])(SMEM + 131072);

  const _Float16* Q = qh + ((size_t)bh * S_ + q) * DK;
  const _Float16* K = kh + (size_t)bh * S_ * DK;
  const _Float16* V = vt + (size_t)bh * DK * S_;
  const float* BIrow = attn_bias + ((size_t)bh * S_ + q0w) * S_;
  const _Float16* MSrow = msk + ((size_t)b * S_ + q0w) * S_;

  half8 qf0 = *(const half8*)(Q + quad * 8);
  half8 qf1 = *(const half8*)(Q + 32 + quad * 8);

  f32x4 acc[4] = {};
  float m_r = -1e38f, l_r = 0.0f;

  auto stage_clump = [&](int tt, int buf) __attribute__((always_inline)) {
    int kb = tt * 64;
    {
      int row = wave * 8 + lr8;
      gload16(K + (size_t)(kb + row) * DK + u8 * 8,
              SMEM + buf * 8192 + wave * 1024);
      gload16(V + (size_t)row * S_ + kb + u8 * 8,
              SMEM + 16384 + buf * 8192 + wave * 1024);
    }
#pragma unroll
    for (int c = 0; c < 4; c++) {
      int row = c * 4 + (lane >> 4);
      int ju = (lane & 15) ^ (row & 7);
      gload16(BIrow + (size_t)row * S_ + kb + ju * 4,
              SMEM + 32768 + buf * 32768 + wave * 4096 + c * 1024);
    }
#pragma unroll
    for (int c = 0; c < 2; c++) {
      int row = c * 8 + lr8;
      gload16(MSrow + (size_t)row * S_ + kb + u8 * 8,
              SMEM + 98304 + buf * 16384 + wave * 2048 + c * 1024);
    }
  };

  stage_clump(0, 0);

  for (int t = 0; t < 16; t++) {
    stage_clump((t + 1) & 15, (t + 1) & 1);

    asm volatile("s_waitcnt vmcnt(8)" ::: "memory");
    __builtin_amdgcn_sched_barrier(0);
    __builtin_amdgcn_s_barrier();

    int buf = t & 1;
    _Float16* Klds = (_Float16*)(SMEM + buf * 8192);
    _Float16* Vlds = (_Float16*)(SMEM + 16384 + buf * 8192);
    float* Bw = (float*)(SMEM + 32768 + buf * 32768 + wave * 4096);
    _Float16* Mw = (_Float16*)(SMEM + 98304 + buf * 16384 + wave * 2048);

#pragma unroll
    for (int hf = 0; hf < 2; hf++) {
      int kcl = hf * 32;
      int R0 = kcl + col, R1 = kcl + 16 + col;
      half8 kf00 = *(const half8*)&Klds[R0 * 64 + ((quad ^ xr) << 3)];
      half8 kf01 = *(const half8*)&Klds[R0 * 64 + (((quad + 4) ^ xr) << 3)];
      half8 kf10 = *(const half8*)&Klds[R1 * 64 + ((quad ^ xr) << 3)];
      half8 kf11 = *(const half8*)&Klds[R1 * 64 + (((quad + 4) ^ xr) << 3)];

      int ku = (kcl >> 3) + quad;
      half8 vf0 = *(const half8*)&Vlds[(0 * 16 + col) * 64 + ((ku ^ xr) << 3)];
      half8 vf1 = *(const half8*)&Vlds[(1 * 16 + col) * 64 + ((ku ^ xr) << 3)];
      half8 vf2 = *(const half8*)&Vlds[(2 * 16 + col) * 64 + ((ku ^ xr) << 3)];
      half8 vf3 = *(const half8*)&Vlds[(3 * 16 + col) * 64 + ((ku ^ xr) << 3)];

      int jb = kcl >> 2;
      f32x4 bi0 = *(const f32x4*)&Bw[col * 64 + (((jb + quad) ^ xr) << 2)];
      f32x4 bi1 = *(const f32x4*)&Bw[col * 64 + (((jb + 4 + quad) ^ xr) << 2)];
      int jm = (kcl >> 3) + (quad >> 1);
      half4 mk0 = *(const half4*)&Mw[col * 64 + ((jm ^ xr) << 3) + (quad & 1) * 4];
      half4 mk1 = *(const half4*)&Mw[col * 64 + (((jm + 2) ^ xr) << 3) + (quad & 1) * 4];

      // QK^T swapped: S^T[k][q] — T5: boost MFMA cluster priority
      __builtin_amdgcn_s_setprio(1);
      f32x4 s0 = {}, s1 = {};
      s0 = __builtin_amdgcn_mfma_f32_16x16x32_f16(kf00, qf0, s0, 0, 0, 0);
      s0 = __builtin_amdgcn_mfma_f32_16x16x32_f16(kf01, qf1, s0, 0, 0, 0);
      s1 = __builtin_amdgcn_mfma_f32_16x16x32_f16(kf10, qf0, s1, 0, 0, 0);
      s1 = __builtin_amdgcn_mfma_f32_16x16x32_f16(kf11, qf1, s1, 0, 0, 0);
      __builtin_amdgcn_s_setprio(0);

      float x0[4], x1[4];
#pragma unroll
      for (int r = 0; r < 4; r++) {
        x0[r] = s0[r] + bi0[r] + (float)mk0[r];
        x1[r] = s1[r] + bi1[r] + (float)mk1[r];
      }

      float mx = fmaxf(fmaxf(fmaxf(x0[0], x0[1]), fmaxf(x0[2], x0[3])),
                       fmaxf(fmaxf(x1[0], x1[1]), fmaxf(x1[2], x1[3])));
      mx = fmaxf(mx, __shfl_xor(mx, 16));
      mx = fmaxf(mx, __shfl_xor(mx, 32));
      float mnew = fmaxf(m_r, mx);
      float f = __expf(m_r - mnew);
      float p0[4], p1[4];
      float ps = 0.0f;
#pragma unroll
      for (int r = 0; r < 4; r++) {
        p0[r] = __expf(x0[r] - mnew);
        p1[r] = __expf(x1[r] - mnew);
        ps += p0[r] + p1[r];
      }
      ps += __shfl_xor(ps, 16);
      ps += __shfl_xor(ps, 32);
      l_r = l_r * f + ps;
      m_r = mnew;
#pragma unroll
      for (int nt = 0; nt < 4; nt++) acc[nt] *= f;

      half2_t c0 = {(_Float16)p0[0], (_Float16)p0[1]};
      half2_t c1 = {(_Float16)p0[2], (_Float16)p0[3]};
      half2_t c2 = {(_Float16)p1[0], (_Float16)p1[1]};
      half2_t c3 = {(_Float16)p1[2], (_Float16)p1[3]};
      P2[wave][col][quad * 2 + 0] = __builtin_bit_cast(unsigned, c0);
      P2[wave][col][quad * 2 + 1] = __builtin_bit_cast(unsigned, c1);
      P2[wave][col][8 + quad * 2 + 0] = __builtin_bit_cast(unsigned, c2);
      P2[wave][col][8 + quad * 2 + 1] = __builtin_bit_cast(unsigned, c3);

      half8 pf = *(const half8*)&P2[wave][col][quad * 4];

      __builtin_amdgcn_s_setprio(1);
      acc[0] = __builtin_amdgcn_mfma_f32_16x16x32_f16(vf0, pf, acc[0], 0, 0, 0);
      acc[1] = __builtin_amdgcn_mfma_f32_16x16x32_f16(vf1, pf, acc[1], 0, 0, 0);
      acc[2] = __builtin_amdgcn_mfma_f32_16x16x32_f16(vf2, pf, acc[2], 0, 0, 0);
      acc[3] = __builtin_amdgcn_mfma_f32_16x16x32_f16(vf3, pf, acc[3], 0, 0, 0);
      __builtin_amdgcn_s_setprio(0);
    }
    __builtin_amdgcn_s_barrier();
  }
  asm volatile("s_waitcnt vmcnt(0)" ::: "memory");

  float linv = 1.0f / l_r;
  _Float16* aop = ao + (size_t)(b * S_ + q) * HIDDEN + h * DK;
#pragma unroll
  for (int nt = 0; nt < 4; nt++)
#pragma unroll
    for (int rp = 0; rp < 2; rp++) {
      int d = nt * 16 + quad * 4 + rp * 2;
      half2_t o = {(_Float16)(acc[nt][rp * 2] * linv),
                   (_Float16)(acc[nt][rp * 2 + 1] * linv)};
      *(half2_t*)(aop + d) = o;
    }
}

// ---------------- output projection v2: staged-GEMM template ----------------
__global__ __launch_bounds__(256) void out_proj2(
    const _Float16* __restrict__ ao, const _Float16* __restrict__ wo,
    const float* __restrict__ bo, float* __restrict__ out) {
  int m0 = blockIdx.x * 64;
  int n0 = blockIdx.y * 64;
  int tid = threadIdx.x, wave = tid >> 6, lane = tid & 63;
  int r16 = lane & 15, quad = lane >> 4;

  __shared__ __align__(16) char SM[16384];
  int rl = lane >> 2;
  int ku = lane & 3;
  int kup = ku ^ ((rl >> 1) & 3);

  const _Float16* Xg = ao + (size_t)(m0 + wave * 16 + rl) * HIDDEN + kup * 8;
  const _Float16* Wg = wo + (size_t)(n0 + wave * 16 + rl) * HIDDEN + kup * 8;

  auto stage = [&](int k0, int buf) __attribute__((always_inline)) {
    gload16(Xg + k0, SM + buf * 4096 + wave * 1024);
    gload16(Wg + k0, SM + 8192 + buf * 4096 + wave * 1024);
  };

  f32x4 acc[4] = {};
  stage(0, 0);
  int sw = (r16 >> 1) & 3;

  for (int t = 0; t < 16; t++) {
    int k0n = (t < 15) ? (t + 1) * 32 : 0;
    stage(k0n, (t + 1) & 1);
    asm volatile("s_waitcnt vmcnt(2)" ::: "memory");
    __builtin_amdgcn_sched_barrier(0);
    __builtin_amdgcn_s_barrier();

    int buf = t & 1;
    const _Float16* XT = (const _Float16*)(SM + buf * 4096);
    const _Float16* WT = (const _Float16*)(SM + 8192 + buf * 4096);
    half8 a = *(const half8*)&XT[(wave * 16 + r16) * 32 + ((quad ^ sw) << 3)];
#pragma unroll
    for (int nt = 0; nt < 4; nt++) {
      half8 bfr = *(const half8*)&WT[(nt * 16 + r16) * 32 + ((quad ^ sw) << 3)];
      acc[nt] = __builtin_amdgcn_mfma_f32_16x16x32_f16(a, bfr, acc[nt], 0, 0, 0);
    }
    __builtin_amdgcn_s_barrier();
  }
  asm volatile("s_waitcnt vmcnt(0)" ::: "memory");

#pragma unroll
  for (int nt = 0; nt < 4; nt++) {
    int gcol = n0 + nt * 16 + r16;
    float bv_ = bo[gcol];
#pragma unroll
    for (int r = 0; r < 4; r++) {
      int grow = m0 + wave * 16 + quad * 4 + r;
      out[grow * HIDDEN + gcol] = acc[nt][r] + bv_;
    }
  }
}

// ---------------- launch ----------------
extern "C" void kernel_launch(void* const* d_in, const int* in_sizes, int n_in,
                              void* d_out, int out_size, void* d_ws, size_t ws_size,
                              hipStream_t stream) {
  const float* q = (const float*)d_in[0];
  const float* k = (const float*)d_in[1];
  const float* v = (const float*)d_in[2];
  const float* attn_bias = (const float*)d_in[3];
  const int* gmask = (const int*)d_in[4];
  const float* subsq = (const float*)d_in[5];
  const float* Wq = (const float*)d_in[6];
  const float* bq = (const float*)d_in[7];
  const float* Wk = (const float*)d_in[8];
  const float* bk = (const float*)d_in[9];
  const float* Wv = (const float*)d_in[10];
  const float* bv = (const float*)d_in[11];
  const float* Wo = (const float*)d_in[12];
  const float* bo = (const float*)d_in[13];

  char* ws = (char*)d_ws;
  _Float16* q16 = (_Float16*)(ws + 0);
  _Float16* k16 = (_Float16*)(ws + 4194304);
  _Float16* v16 = (_Float16*)(ws + 8388608);
  _Float16* wq16 = (_Float16*)(ws + 12582912);
  _Float16* wk16 = (_Float16*)(ws + 13107200);
  _Float16* wv16 = (_Float16*)(ws + 13631488);
  _Float16* wo16 = (_Float16*)(ws + 14155776);
  _Float16* qhb = (_Float16*)(ws + 14680064);
  _Float16* khb = (_Float16*)(ws + 18874368);
  _Float16* vtb = (_Float16*)(ws + 23068672);
  _Float16* aob = (_Float16*)(ws + 27262976);
  _Float16* msk16 = (_Float16*)(ws + 31457280);  // 8 MB, separate region

  prep<<<dim3(11264), 256, 0, stream>>>(q, k, v, Wq, Wk, Wv, Wo, gmask, subsq,
                                        q16, k16, v16, wq16, wk16, wv16, wo16,
                                        msk16);
  proj_qkv2<<<dim3(64, 24), 256, 0, stream>>>(q16, k16, v16, wq16, wk16, wv16,
                                              bq, bk, bv, qhb, khb, vtb);
  attn13<<<dim3(256), 512, 0, stream>>>(qhb, khb, vtb, attn_bias, msk16, aob);
  out_proj2<<<dim3(64, 8), 256, 0, stream>>>(aob, wo16, bo, (float*)d_out);
}